// Round 11
// baseline (6332.592 us; speedup 1.0000x reference)
//
#include <hip/hip_runtime.h>

#define Bn 32
#define Tn 2048
#define Hn 256
#define DEPTHn 4

typedef unsigned short u16;
typedef u16      us8 __attribute__((ext_vector_type(8)));
typedef _Float16 h8  __attribute__((ext_vector_type(8)));
typedef float    f4  __attribute__((ext_vector_type(4)));

__device__ __forceinline__ u16 f2h(float x) {
    return __builtin_bit_cast(u16, (_Float16)x);
}
__device__ __forceinline__ unsigned int pk2(float a, float b) {
    return __builtin_bit_cast(unsigned int, __builtin_amdgcn_cvt_pkrtz(a, b));
}

// ---------------------------------------------------------------------------
// Phase A: Z[b,t,:] = in[b,t,:] @ Wx + bias. Register-tiled 8x8 fp32.
// (unchanged — known good, ~110 µs per dispatch)
// ---------------------------------------------------------------------------
#define GR 64
__global__ __launch_bounds__(256, 2) void gemm_xw(
    const float* __restrict__ in, long in_bstride,
    const float* __restrict__ Wx, const float* __restrict__ bias,
    float* __restrict__ Z)
{
    __shared__ __align__(16) float a_lds[GR][264];

    const int tid = threadIdx.x;
    const int row0 = blockIdx.x * GR;

    #pragma unroll
    for (int q = 0; q < 16; ++q) {
        int f = tid + q * 256;
        int r  = f >> 6;
        int c4 = f & 63;
        int grow = row0 + r;
        int b = grow >> 11;
        int t = grow & (Tn - 1);
        float4 v = *(const float4*)(in + (long)b * in_bstride + (long)t * Hn + c4 * 4);
        *(float4*)(&a_lds[r][c4 * 4]) = v;
    }
    __syncthreads();

    const int g  = tid >> 5;
    const int cg = tid & 31;

    float acc[8][8];
    #pragma unroll
    for (int i = 0; i < 8; ++i)
        #pragma unroll
        for (int j = 0; j < 8; ++j) acc[i][j] = 0.f;

    for (int k4 = 0; k4 < 64; ++k4) {
        float4 w[4][2];
        #pragma unroll
        for (int kk = 0; kk < 4; ++kk) {
            const float* wr = Wx + (long)(k4 * 4 + kk) * Hn + cg * 8;
            w[kk][0] = *(const float4*)(wr);
            w[kk][1] = *(const float4*)(wr + 4);
        }
        float4 a[8];
        #pragma unroll
        for (int i = 0; i < 8; ++i)
            a[i] = *(const float4*)(&a_lds[i * 8 + g][k4 * 4]);

        #pragma unroll
        for (int i = 0; i < 8; ++i) {
            #pragma unroll
            for (int kk = 0; kk < 4; ++kk) {
                float av = ((const float*)&a[i])[kk];
                acc[i][0] = fmaf(av, w[kk][0].x, acc[i][0]);
                acc[i][1] = fmaf(av, w[kk][0].y, acc[i][1]);
                acc[i][2] = fmaf(av, w[kk][0].z, acc[i][2]);
                acc[i][3] = fmaf(av, w[kk][0].w, acc[i][3]);
                acc[i][4] = fmaf(av, w[kk][1].x, acc[i][4]);
                acc[i][5] = fmaf(av, w[kk][1].y, acc[i][5]);
                acc[i][6] = fmaf(av, w[kk][1].z, acc[i][6]);
                acc[i][7] = fmaf(av, w[kk][1].w, acc[i][7]);
            }
        }
    }

    float4 b0 = *(const float4*)(bias + cg * 8);
    float4 b1 = *(const float4*)(bias + cg * 8 + 4);
    #pragma unroll
    for (int i = 0; i < 8; ++i) {
        long row = row0 + i * 8 + g;
        float4 o0 = { acc[i][0] + b0.x, acc[i][1] + b0.y, acc[i][2] + b0.z, acc[i][3] + b0.w };
        float4 o1 = { acc[i][4] + b1.x, acc[i][5] + b1.y, acc[i][6] + b1.z, acc[i][7] + b1.w };
        *(float4*)(Z + row * Hn + cg * 8)     = o0;
        *(float4*)(Z + row * Hn + cg * 8 + 4) = o1;
    }
}

// ---------------------------------------------------------------------------
// Phase B: h_t = tanh(Z[t] + h_{t-d} @ Wh) — 16 streams per workgroup, MFMA
// computes C[ch][stream] = Wh^T · H so ALL 16 MFMA columns are useful work.
// 256 threads = 4 waves; wave wv owns ch [64wv, 64wv+64) as 4 blocks of 16.
// A-operand (per lane g=lane>>4, c=lane&15): Wh[k=32cc+8g+i][64wv+16j+c]
// (f16). CRITICAL: keeping the 128-VGPR Af array live across the loop needs
// (a) amdgpu_waves_per_eu(1,1) — raises the backend's register budget /
// pressure target to the full 512 (launch_bounds(256,1) is a no-op: R10 ==
// R9 byte-identical; default pressure heuristic re-materialized the weight
// loads EVERY step, ~45% VALU-busy on active CUs), and (b) empty-asm pins
// after init so the loads can't be sunk into the loop (rule #17 idiom).
// B-operand: h_stream(c)[32cc+8g+i] read as one ds_read_b128 per cc from
// row-padded LDS (stride 264 u16; 2-way lane aliasing = free).
// C layout (HW-verified): col=lane&15 = stream c, row=4g+reg = ch-sub ->
// lane (g,c) produces stream c, chs 64wv+16j+4g+[0,4): contiguous -> float4
// out-store, uint2 LDS h-write, float4 z-load. Grid = 2*dilation WGs.
// Sync: fused "s_waitcnt lgkmcnt(0); s_barrier" (proven R6-R10); z prefetch
// and out stores stay in flight across steps.
// ---------------------------------------------------------------------------
__global__ __launch_bounds__(256)
__attribute__((amdgpu_waves_per_eu(1, 1)))
void rnn_layer(
    const float* __restrict__ Z,
    const float* __restrict__ Wh,       // [256,256] this layer, fp32
    float* __restrict__ out,            // d_out + jL*Tn*Hn; batch stride 4*Tn*Hn
    const int* __restrict__ seq_lens,
    int dilation, int logd)
{
    __shared__ __align__(16) u16 hb[2][16][264];   // [buf][stream][ch padded]

    const int tid  = threadIdx.x;
    const int wv   = tid >> 6;          // 0..3
    const int lane = tid & 63;
    const int g    = lane >> 4;         // 0..3
    const int c    = lane & 15;         // 0..15 : stream within WG

    const int sid = blockIdx.x * 16 + c;          // global stream id
    const int b   = sid >> logd;
    const int r   = sid & (dilation - 1);

    // A fragments: Af[j][cc] = Wh[32cc+8g+i][64wv+16j+c] as f16, i=0..7
    us8 Af[4][8];
    #pragma unroll
    for (int j = 0; j < 4; ++j) {
        #pragma unroll
        for (int cc = 0; cc < 8; ++cc) {
            const float* wp = Wh + (long)(32 * cc + 8 * g) * Hn + (64 * wv + 16 * j + c);
            us8 v;
            #pragma unroll
            for (int i = 0; i < 8; ++i) v[i] = f2h(wp[(long)i * Hn]);
            Af[j][cc] = v;
        }
    }
    // Pin every fragment in registers BEFORE the loop: an explicit pre-loop
    // use forbids sinking the load+cvt chain into the loop body.
    #pragma unroll
    for (int j = 0; j < 4; ++j)
        #pragma unroll
        for (int cc = 0; cc < 8; ++cc)
            asm volatile("" : "+v"(Af[j][cc]));

    // zero both h buffers: 2*16*264 u16 = 4224 u32
    for (int i = tid; i < 4224; i += 256) ((unsigned int*)hb)[i] = 0u;
    const int L = seq_lens[b];
    __syncthreads();

    const long bTH = (long)Tn * Hn;
    const float* zp = Z   + (long)b * bTH            + (long)r * Hn + (64 * wv + 4 * g);
    float*       op = out + (long)b * (DEPTHn * bTH) + (long)r * Hn + (64 * wv + 4 * g);
    const long step_off = (long)dilation * Hn;

    const int steps = Tn >> logd;
    int cur = 0;
    int t = r;

    float4 zc[4], zn[4];
    #pragma unroll
    for (int j = 0; j < 4; ++j) zc[j] = *(const float4*)(zp + 16 * j);
    zp += step_off;

    for (int k = 0; k < steps; ++k) {
        if (k + 1 < steps) {                       // prefetch next step's z
            #pragma unroll
            for (int j = 0; j < 4; ++j) zn[j] = *(const float4*)(zp + 16 * j);
            zp += step_off;
        }

        // B fragments: h of this step (stream c, k chunk per cc)
        const u16* hp = &hb[cur][c][0];
        h8 hv[8];
        #pragma unroll
        for (int cc = 0; cc < 8; ++cc)
            hv[cc] = __builtin_bit_cast(h8, *(const us8*)(hp + 32 * cc + 8 * g));

        u16* hw = &hb[cur ^ 1][c][64 * wv + 4 * g];
        const bool valid = (t < L);

        #pragma unroll
        for (int j = 0; j < 4; ++j) {
            f4 a0 = { 0.f, 0.f, 0.f, 0.f }, a1 = { 0.f, 0.f, 0.f, 0.f };
            #pragma unroll
            for (int cc = 0; cc < 8; cc += 2) {
                a0 = __builtin_amdgcn_mfma_f32_16x16x32_f16(
                         __builtin_bit_cast(h8, Af[j][cc]),     hv[cc],     a0, 0, 0, 0);
                a1 = __builtin_amdgcn_mfma_f32_16x16x32_f16(
                         __builtin_bit_cast(h8, Af[j][cc + 1]), hv[cc + 1], a1, 0, 0, 0);
            }
            float y0 = a0[0] + a1[0] + zc[j].x;
            float y1 = a0[1] + a1[1] + zc[j].y;
            float y2 = a0[2] + a1[2] + zc[j].z;
            float y3 = a0[3] + a1[3] + zc[j].w;
            float h0 = 1.f - 2.f / (__expf(2.f * y0) + 1.f);   // saturates at +/-inf
            float h1 = 1.f - 2.f / (__expf(2.f * y1) + 1.f);
            float h2 = 1.f - 2.f / (__expf(2.f * y2) + 1.f);
            float h3 = 1.f - 2.f / (__expf(2.f * y3) + 1.f);
            float4 ov;
            ov.x = valid ? h0 : 0.f;
            ov.y = valid ? h1 : 0.f;
            ov.z = valid ? h2 : 0.f;
            ov.w = valid ? h3 : 0.f;
            *(float4*)(op + 16 * j) = ov;          // masked out-store (in flight)
            uint2 pw = { pk2(h0, h1), pk2(h2, h3) };
            *(uint2*)(hw + 16 * j) = pw;           // unmasked h -> next buffer
        }
        op += step_off;

        // fused LDS-drain + barrier: one opaque memory op, nothing crosses it
        asm volatile("s_waitcnt lgkmcnt(0)\n\ts_barrier" ::: "memory");
        cur ^= 1;
        t += dilation;
        #pragma unroll
        for (int j = 0; j < 4; ++j) zc[j] = zn[j];
    }
}

// ---------------------------------------------------------------------------
extern "C" void kernel_launch(void* const* d_in, const int* in_sizes, int n_in,
                              void* d_out, int out_size, void* d_ws, size_t ws_size,
                              hipStream_t stream) {
    const float* x    = (const float*)d_in[0];   // [B,T,H]
    const float* Wx   = (const float*)d_in[1];   // [4,H,H]
    const float* Wh   = (const float*)d_in[2];   // [4,H,H]
    const float* bias = (const float*)d_in[3];   // [4,H]
    const int*   seq  = (const int*)  d_in[4];   // [B]
    float* out = (float*)d_out;                  // [B,4,T,H]
    float* Z   = (float*)d_ws;                   // [B,T,H] scratch (64 MB)

    for (int j = 0; j < DEPTHn; ++j) {
        const float* in;
        long bstride;
        if (j == 0) { in = x;                             bstride = (long)Tn * Hn; }
        else        { in = out + (long)(j - 1) * Tn * Hn; bstride = (long)DEPTHn * Tn * Hn; }

        hipLaunchKernelGGL(gemm_xw, dim3(Bn * Tn / GR), dim3(256), 0, stream,
                           in, bstride, Wx + (long)j * Hn * Hn, bias + (long)j * Hn, Z);

        int d = 1 << j;
        hipLaunchKernelGGL(rnn_layer, dim3(2 * d), dim3(256), 0, stream,
                           Z, Wh + (long)j * Hn * Hn, out + (long)j * Tn * Hn, seq, d, j);
    }
}

// Round 13
// 5481.201 us; speedup vs baseline: 1.1553x; 1.1553x over previous
//
#include <hip/hip_runtime.h>

#define Bn 32
#define Tn 2048
#define Hn 256
#define DEPTHn 4

typedef unsigned short u16;
typedef u16      us8 __attribute__((ext_vector_type(8)));
typedef _Float16 h8  __attribute__((ext_vector_type(8)));
typedef float    f4  __attribute__((ext_vector_type(4)));

__device__ __forceinline__ u16 f2h(float x) {
    return __builtin_bit_cast(u16, (_Float16)x);
}
__device__ __forceinline__ unsigned int pk2(float a, float b) {
    return __builtin_bit_cast(unsigned int, __builtin_amdgcn_cvt_pkrtz(a, b));
}

// ---------------------------------------------------------------------------
// Phase A: Z[b,t,:] = in[b,t,:] @ Wx + bias. Register-tiled 8x8 fp32.
// (unchanged — known good, ~110 µs per dispatch)
// ---------------------------------------------------------------------------
#define GR 64
__global__ __launch_bounds__(256, 2) void gemm_xw(
    const float* __restrict__ in, long in_bstride,
    const float* __restrict__ Wx, const float* __restrict__ bias,
    float* __restrict__ Z)
{
    __shared__ __align__(16) float a_lds[GR][264];

    const int tid = threadIdx.x;
    const int row0 = blockIdx.x * GR;

    #pragma unroll
    for (int q = 0; q < 16; ++q) {
        int f = tid + q * 256;
        int r  = f >> 6;
        int c4 = f & 63;
        int grow = row0 + r;
        int b = grow >> 11;
        int t = grow & (Tn - 1);
        float4 v = *(const float4*)(in + (long)b * in_bstride + (long)t * Hn + c4 * 4);
        *(float4*)(&a_lds[r][c4 * 4]) = v;
    }
    __syncthreads();

    const int g  = tid >> 5;
    const int cg = tid & 31;

    float acc[8][8];
    #pragma unroll
    for (int i = 0; i < 8; ++i)
        #pragma unroll
        for (int j = 0; j < 8; ++j) acc[i][j] = 0.f;

    for (int k4 = 0; k4 < 64; ++k4) {
        float4 w[4][2];
        #pragma unroll
        for (int kk = 0; kk < 4; ++kk) {
            const float* wr = Wx + (long)(k4 * 4 + kk) * Hn + cg * 8;
            w[kk][0] = *(const float4*)(wr);
            w[kk][1] = *(const float4*)(wr + 4);
        }
        float4 a[8];
        #pragma unroll
        for (int i = 0; i < 8; ++i)
            a[i] = *(const float4*)(&a_lds[i * 8 + g][k4 * 4]);

        #pragma unroll
        for (int i = 0; i < 8; ++i) {
            #pragma unroll
            for (int kk = 0; kk < 4; ++kk) {
                float av = ((const float*)&a[i])[kk];
                acc[i][0] = fmaf(av, w[kk][0].x, acc[i][0]);
                acc[i][1] = fmaf(av, w[kk][0].y, acc[i][1]);
                acc[i][2] = fmaf(av, w[kk][0].z, acc[i][2]);
                acc[i][3] = fmaf(av, w[kk][0].w, acc[i][3]);
                acc[i][4] = fmaf(av, w[kk][1].x, acc[i][4]);
                acc[i][5] = fmaf(av, w[kk][1].y, acc[i][5]);
                acc[i][6] = fmaf(av, w[kk][1].z, acc[i][6]);
                acc[i][7] = fmaf(av, w[kk][1].w, acc[i][7]);
            }
        }
    }

    float4 b0 = *(const float4*)(bias + cg * 8);
    float4 b1 = *(const float4*)(bias + cg * 8 + 4);
    #pragma unroll
    for (int i = 0; i < 8; ++i) {
        long row = row0 + i * 8 + g;
        float4 o0 = { acc[i][0] + b0.x, acc[i][1] + b0.y, acc[i][2] + b0.z, acc[i][3] + b0.w };
        float4 o1 = { acc[i][4] + b1.x, acc[i][5] + b1.y, acc[i][6] + b1.z, acc[i][7] + b1.w };
        *(float4*)(Z + row * Hn + cg * 8)     = o0;
        *(float4*)(Z + row * Hn + cg * 8 + 4) = o1;
    }
}

// ---------------------------------------------------------------------------
// Phase B: h_t = tanh(Z[t] + h_{t-d} @ Wh) — 16 streams/WG, C = Wh^T · H via
// intrinsic MFMA (hazard-safe; R9's operand mapping passed correctness).
// 512 threads = 8 waves: wave wv owns chs [32wv, 32wv+32) as 2 blocks of 16
// -> Af = 2x8 us8 = 64 VGPR/lane (total demand ~150, BELOW the ~210-demand
// spill cliff that crippled R9-R12's 4-wave/128-VGPR layout).
// A (lane g=lane>>4, c=lane&15): Wh[k=32cc+8g+i][32wv+16j+c] f16 in VGPRs.
// B: h_stream(c)[32cc+8g+i], one b128 read per cc from blocked LDS
// hb[buf][cc][stream][40] (16B-aligned rows, ~2 rows/bank => near-free).
// C (HW-verified): col=lane&15 = stream c, row=4g+reg -> lane (g,c) produces
// stream c, chs 32wv+16j+4g+[0,4): contiguous float4 out-store + uint2 LDS
// h-write into chunk cc'=wv. Grid = 2*dilation WGs.
// Sync: fused "s_waitcnt lgkmcnt(0); s_barrier" (proven R6-R11); z prefetch
// and out stores stay in flight across steps.
// ---------------------------------------------------------------------------
__global__ __launch_bounds__(512) void rnn_layer(
    const float* __restrict__ Z,
    const float* __restrict__ Wh,       // [256,256] this layer, fp32
    float* __restrict__ out,            // d_out + jL*Tn*Hn; batch stride 4*Tn*Hn
    const int* __restrict__ seq_lens,
    int dilation, int logd)
{
    __shared__ __align__(16) u16 hb[2][8][16][40];   // [buf][k-chunk][stream][32+pad]

    const int tid  = threadIdx.x;
    const int wv   = tid >> 6;          // 0..7
    const int lane = tid & 63;
    const int g    = lane >> 4;         // 0..3
    const int c    = lane & 15;         // 0..15 : stream within WG

    const int sid = blockIdx.x * 16 + c;          // global stream id
    const int b   = sid >> logd;
    const int r   = sid & (dilation - 1);

    // A fragments: Af[j][cc] = Wh[32cc+8g+i][32wv+16j+c] as f16, i=0..7
    us8 Af[2][8];
    #pragma unroll
    for (int j = 0; j < 2; ++j) {
        #pragma unroll
        for (int cc = 0; cc < 8; ++cc) {
            const float* wp = Wh + (long)(32 * cc + 8 * g) * Hn + (32 * wv + 16 * j + c);
            us8 v;
            #pragma unroll
            for (int i = 0; i < 8; ++i) v[i] = f2h(wp[(long)i * Hn]);
            Af[j][cc] = v;
        }
    }

    // zero both h buffers: 2*8*16*40 u16 = 5120 u32
    for (int i = tid; i < 5120; i += 512) ((unsigned int*)hb)[i] = 0u;
    const int L = seq_lens[b];
    __syncthreads();

    const long bTH = (long)Tn * Hn;
    const float* zp = Z   + (long)b * bTH            + (long)r * Hn + (32 * wv + 4 * g);
    float*       op = out + (long)b * (DEPTHn * bTH) + (long)r * Hn + (32 * wv + 4 * g);
    const long step_off = (long)dilation * Hn;

    const int steps = Tn >> logd;
    int cur = 0;
    int t = r;

    float4 zc[2], zn[2];
    #pragma unroll
    for (int j = 0; j < 2; ++j) zc[j] = *(const float4*)(zp + 16 * j);
    zp += step_off;

    for (int k = 0; k < steps; ++k) {
        if (k + 1 < steps) {                       // prefetch next step's z
            #pragma unroll
            for (int j = 0; j < 2; ++j) zn[j] = *(const float4*)(zp + 16 * j);
            zp += step_off;
        }

        // B fragments: h of this step (stream c, k chunk (cc, g))
        us8 hv[8];
        #pragma unroll
        for (int cc = 0; cc < 8; ++cc)
            hv[cc] = *(const us8*)(&hb[cur][cc][c][8 * g]);

        const bool valid = (t < L);

        #pragma unroll
        for (int j = 0; j < 2; ++j) {
            f4 a0 = { 0.f, 0.f, 0.f, 0.f }, a1 = { 0.f, 0.f, 0.f, 0.f };
            #pragma unroll
            for (int cc = 0; cc < 8; cc += 2) {
                a0 = __builtin_amdgcn_mfma_f32_16x16x32_f16(
                         __builtin_bit_cast(h8, Af[j][cc]),
                         __builtin_bit_cast(h8, hv[cc]),     a0, 0, 0, 0);
                a1 = __builtin_amdgcn_mfma_f32_16x16x32_f16(
                         __builtin_bit_cast(h8, Af[j][cc + 1]),
                         __builtin_bit_cast(h8, hv[cc + 1]), a1, 0, 0, 0);
            }
            float y0 = a0[0] + a1[0] + zc[j].x;
            float y1 = a0[1] + a1[1] + zc[j].y;
            float y2 = a0[2] + a1[2] + zc[j].z;
            float y3 = a0[3] + a1[3] + zc[j].w;
            float h0 = 1.f - 2.f / (__expf(2.f * y0) + 1.f);   // saturates at +/-inf
            float h1 = 1.f - 2.f / (__expf(2.f * y1) + 1.f);
            float h2 = 1.f - 2.f / (__expf(2.f * y2) + 1.f);
            float h3 = 1.f - 2.f / (__expf(2.f * y3) + 1.f);
            float4 ov;
            ov.x = valid ? h0 : 0.f;
            ov.y = valid ? h1 : 0.f;
            ov.z = valid ? h2 : 0.f;
            ov.w = valid ? h3 : 0.f;
            *(float4*)(op + 16 * j) = ov;          // masked out-store (in flight)
            uint2 pw = { pk2(h0, h1), pk2(h2, h3) };
            // k-base = 32wv+16j+4g -> chunk wv, within-chunk 16j+4g
            *(uint2*)(&hb[cur ^ 1][wv][c][16 * j + 4 * g]) = pw;
        }
        op += step_off;

        // fused LDS-drain + barrier: one opaque memory op, nothing crosses it
        asm volatile("s_waitcnt lgkmcnt(0)\n\ts_barrier" ::: "memory");
        cur ^= 1;
        t += dilation;
        #pragma unroll
        for (int j = 0; j < 2; ++j) zc[j] = zn[j];
    }
}

// ---------------------------------------------------------------------------
extern "C" void kernel_launch(void* const* d_in, const int* in_sizes, int n_in,
                              void* d_out, int out_size, void* d_ws, size_t ws_size,
                              hipStream_t stream) {
    const float* x    = (const float*)d_in[0];   // [B,T,H]
    const float* Wx   = (const float*)d_in[1];   // [4,H,H]
    const float* Wh   = (const float*)d_in[2];   // [4,H,H]
    const float* bias = (const float*)d_in[3];   // [4,H]
    const int*   seq  = (const int*)  d_in[4];   // [B]
    float* out = (float*)d_out;                  // [B,4,T,H]
    float* Z   = (float*)d_ws;                   // [B,T,H] scratch (64 MB)

    for (int j = 0; j < DEPTHn; ++j) {
        const float* in;
        long bstride;
        if (j == 0) { in = x;                             bstride = (long)Tn * Hn; }
        else        { in = out + (long)(j - 1) * Tn * Hn; bstride = (long)DEPTHn * Tn * Hn; }

        hipLaunchKernelGGL(gemm_xw, dim3(Bn * Tn / GR), dim3(256), 0, stream,
                           in, bstride, Wx + (long)j * Hn * Hn, bias + (long)j * Hn, Z);

        int d = 1 << j;
        hipLaunchKernelGGL(rnn_layer, dim3(2 * d), dim3(512), 0, stream,
                           Z, Wh + (long)j * Hn * Hn, out + (long)j * Tn * Hn, seq, d, j);
    }
}